// Round 2
// baseline (253.931 us; speedup 1.0000x reference)
//
#include <hip/hip_runtime.h>

// SynthesisStage: modulated conv2d w/ adaptive kernel selection.
// B=8, Ci=Co=256, H=W=128, K=3, N=4.
// v2: no x-transpose scratch (ws needs only 9.44 MB for wmod).
// conv_k fuses the NCHW->[w][ci] transpose into LDS B-staging.

typedef __attribute__((ext_vector_type(4))) float f32x4;
typedef __attribute__((ext_vector_type(8))) short s16x8;
typedef __attribute__((ext_vector_type(4))) unsigned int u32x4;

#define NB   8
#define NCI  256
#define NCO  256
#define NHW  128
#define NKER 4

__device__ __forceinline__ unsigned short f2bf(float f) {
  unsigned int u = __builtin_bit_cast(unsigned int, f);
  u += 0x7FFFu + ((u >> 16) & 1u);          // round-to-nearest-even
  return (unsigned short)(u >> 16);
}

// ---------------------------------------------------------------------------
// Kernel 1: per-sample modulated+demodulated weights -> bf16 wmod[b][tap][co][ci]
// grid = B*Co blocks of 256 threads (thread = ci)
// ---------------------------------------------------------------------------
__global__ __launch_bounds__(256) void prep_k(
    const float* __restrict__ weight,    // [N][Co][Ci][3][3]
    const float* __restrict__ styles,    // [B][Ci]
    const float* __restrict__ selector,  // [B][N]
    unsigned short* __restrict__ wmod)   // [B][9][Co][Ci] bf16
{
  int bid = blockIdx.x;
  int b = bid >> 8, co = bid & 255;
  int ci = threadIdx.x;

  float sel[NKER];
#pragma unroll
  for (int n = 0; n < NKER; ++n) sel[n] = selector[b * NKER + n];

  float a[9];
#pragma unroll
  for (int j = 0; j < 9; ++j) a[j] = 0.f;
#pragma unroll
  for (int n = 0; n < NKER; ++n) {
    const float* wp = weight + (size_t)((n * NCO + co) * NCI + ci) * 9;
    float s = sel[n];
#pragma unroll
    for (int j = 0; j < 9; ++j) a[j] += s * wp[j];
  }
  float st = styles[b * NCI + ci];
  float ss = 0.f;
#pragma unroll
  for (int j = 0; j < 9; ++j) { a[j] *= st; ss += a[j] * a[j]; }

  // block reduction over 256 threads (4 waves)
  for (int off = 32; off; off >>= 1) ss += __shfl_down(ss, off, 64);
  __shared__ float red[4];
  int wid = threadIdx.x >> 6, lane = threadIdx.x & 63;
  if (lane == 0) red[wid] = ss;
  __syncthreads();
  float tot = red[0] + red[1] + red[2] + red[3];
  float d = rsqrtf(tot + 1e-8f);

#pragma unroll
  for (int j = 0; j < 9; ++j)
    wmod[((size_t)(b * 9 + j) * NCO + co) * NCI + ci] = f2bf(a[j] * d);
}

// ---------------------------------------------------------------------------
// Kernel 2: implicit-GEMM conv with fused x-transpose.
// block = (b, co_tile of 128, h). 256 thr = 4 waves (2x2 wave grid, 64x64 out each).
// out[b,co,h,w] = sum_{tap,ci} wmod[b,tap,co,ci] * x[b,ci,h+dh-1,w+dw-1] + noise
// LDS: Al[co 128][ci 64] bf16 (per-tap weights), XR[w 128][ci 64] bf16 (x row),
// both XOR-swizzled (byte ^= (row&7)<<4) for conflict-free ds_read_b128.
// ---------------------------------------------------------------------------
__global__ __launch_bounds__(256, 2) void conv_k(
    const float* __restrict__ x,              // [B][Ci][H][W] f32
    const unsigned short* __restrict__ wm,    // [B][9][Co][Ci] bf16
    const float* __restrict__ noise,          // [B][Co][H][W]
    float* __restrict__ out)                  // [B][Co][H][W]
{
  __shared__ __align__(16) unsigned short Al[128 * 64];
  __shared__ __align__(16) unsigned short XR[128 * 64];

  int bid = blockIdx.x;
  int b = bid >> 8;
  int r = bid & 255;
  int cot = r >> 7;
  int h = r & 127;
  int co0 = cot << 7;

  int t = threadIdx.x;
  int lane = t & 63;
  int wid = t >> 6;
  int wr = wid >> 1, wc = wid & 1;          // 2x2 wave grid

  f32x4 acc[4][4];
#pragma unroll
  for (int m = 0; m < 4; ++m)
#pragma unroll
    for (int n = 0; n < 4; ++n) acc[m][n] = (f32x4){0.f, 0.f, 0.f, 0.f};

  // A staging assignment: 2 threads per co-row, 64B halves
  int srow = t >> 1;
  int shalf = (t & 1) * 64;
  // B staging assignment: thread owns ci-pair (bc, bc+1) x 16 w
  int bc = (t & 31) * 2;                    // local ci pair base, even, [0,64)
  int bwg = t >> 5;                         // w group [bwg*16, +16)

#pragma unroll 1
  for (int dh = 0; dh < 3; ++dh) {
    int hy = h + dh - 1;
    if ((unsigned)hy < (unsigned)NHW) {     // block-uniform: barriers legal inside
#pragma unroll 1
      for (int kb = 0; kb < 4; ++kb) {
        int ci0 = kb << 6;

        __syncthreads();                    // protect previous XR/Al reads
        // ---- stage XR[w][ci'] = bf16(x[b][ci0+ci'][hy][w]) ----
        {
          const f32x4* x40 = (const f32x4*)(x +
              ((size_t)(b * NCI + ci0 + bc) * NHW + hy) * NHW + bwg * 16);
          const f32x4* x41 = (const f32x4*)((const float*)x40 + (size_t)NHW * NHW);
#pragma unroll
          for (int jj = 0; jj < 4; ++jj) {
            f32x4 v0 = x40[jj];
            f32x4 v1 = x41[jj];
#pragma unroll
            for (int e = 0; e < 4; ++e) {
              int w = bwg * 16 + jj * 4 + e;
              unsigned int p = ((unsigned int)f2bf(v1[e]) << 16) | f2bf(v0[e]);
              *(unsigned int*)((char*)XR + w * 128 + ((bc * 2) ^ ((w & 7) << 4))) = p;
            }
          }
        }

#pragma unroll 1
        for (int dw = 0; dw < 3; ++dw) {
          int tap = dh * 3 + dw;
          if (dw > 0) __syncthreads();      // protect Al reads of previous tap
          // ---- stage Al[co'][ci'] = wmod[b][tap][co0+co'][ci0+ci'] ----
          const unsigned short* arow =
              wm + ((size_t)((b * 9 + tap) * NCO) + co0 + srow) * NCI + ci0;
#pragma unroll
          for (int kk = 0; kk < 4; ++kk) {
            int cb = shalf + kk * 16;       // byte col in 128B row
            u32x4 av = *(const u32x4*)(arow + (cb >> 1));
            *(u32x4*)((char*)Al + srow * 128 + (cb ^ ((srow & 7) << 4))) = av;
          }
          __syncthreads();

          // ---- compute: K-tile 64 = 2 MFMA K-steps of 32 ----
#pragma unroll
          for (int ks = 0; ks < 2; ++ks) {
            int cib = ks * 64 + ((lane >> 4) << 4);   // byte offset of lane's 8 bf16
            s16x8 af[4], bf[4];
#pragma unroll
            for (int m = 0; m < 4; ++m) {
              int row = wr * 64 + m * 16 + (lane & 15);
              af[m] = *(const s16x8*)((const char*)Al + row * 128 +
                                      (cib ^ ((row & 7) << 4)));
            }
#pragma unroll
            for (int n = 0; n < 4; ++n) {
              int wn = wc * 64 + n * 16 + (lane & 15) + dw - 1;
              int wx = wn < 0 ? 0 : (wn > 127 ? 127 : wn);
              s16x8 bv = *(const s16x8*)((const char*)XR + wx * 128 +
                                         (cib ^ ((wx & 7) << 4)));
              if (wn != wx) {               // zero padding column
                s16x8 z = {0, 0, 0, 0, 0, 0, 0, 0};
                bv = z;
              }
              bf[n] = bv;
            }
#pragma unroll
            for (int m = 0; m < 4; ++m)
#pragma unroll
              for (int n = 0; n < 4; ++n)
                acc[m][n] = __builtin_amdgcn_mfma_f32_16x16x32_bf16(
                    af[m], bf[n], acc[m][n], 0, 0, 0);
          }
        }
      }
    }
  }

  // epilogue: D[row=(lane>>4)*4+j][col=lane&15], fused noise add
  int pc = lane & 15;
  int pr4 = (lane >> 4) * 4;
#pragma unroll
  for (int m = 0; m < 4; ++m) {
#pragma unroll
    for (int n = 0; n < 4; ++n) {
      int px = wc * 64 + n * 16 + pc;
#pragma unroll
      for (int j = 0; j < 4; ++j) {
        int co = co0 + wr * 64 + m * 16 + pr4 + j;
        size_t idx = ((size_t)(b * NCO + co) * NHW + h) * NHW + px;
        out[idx] = acc[m][n][j] + noise[idx];
      }
    }
  }
}

// ---------------------------------------------------------------------------
extern "C" void kernel_launch(void* const* d_in, const int* in_sizes, int n_in,
                              void* d_out, int out_size, void* d_ws, size_t ws_size,
                              hipStream_t stream) {
  const float* x        = (const float*)d_in[0];
  const float* weight   = (const float*)d_in[1];
  const float* styles   = (const float*)d_in[2];
  const float* selector = (const float*)d_in[3];
  const float* noise    = (const float*)d_in[4];
  float* out = (float*)d_out;

  // workspace: ONLY wmod bf16 [B][9][Co][Ci] = 9,437,184 bytes
  unsigned short* wmod = (unsigned short*)d_ws;

  hipLaunchKernelGGL(prep_k, dim3(NB * NCO), dim3(256), 0, stream,
                     weight, styles, selector, wmod);
  hipLaunchKernelGGL(conv_k, dim3(NB * 2 * NHW), dim3(256), 0, stream,
                     x, wmod, noise, out);
}

// Round 3
// 223.546 us; speedup vs baseline: 1.1359x; 1.1359x over previous
//
#include <hip/hip_runtime.h>

// SynthesisStage: modulated conv2d w/ adaptive kernel selection.
// B=8, Ci=Co=256, H=W=128, K=3, N=4.
// v3: pre-swizzled wmod tiles + global_load_lds for A-staging,
// counted-vmcnt pipeline (never drain), 96-MFMA phases, XCD swizzle.

typedef __attribute__((ext_vector_type(4))) float f32x4;
typedef __attribute__((ext_vector_type(8))) short s16x8;
typedef __attribute__((ext_vector_type(4))) unsigned int u32x4;

#define NB   8
#define NCI  256
#define NCO  256
#define NHW  128
#define NKER 4

__device__ __forceinline__ unsigned short f2bf(float f) {
  unsigned int u = __builtin_bit_cast(unsigned int, f);
  u += 0x7FFFu + ((u >> 16) & 1u);          // round-to-nearest-even
  return (unsigned short)(u >> 16);
}

// global -> LDS direct copy, 16B per lane. lds ptr must be wave-uniform;
// global src is per-lane. Casts via integer per the HK pattern.
__device__ __forceinline__ void gl_lds16(const void* g, void* l) {
  __builtin_amdgcn_global_load_lds(
      (const __attribute__((address_space(1))) void*)(unsigned long long)(uintptr_t)g,
      (__attribute__((address_space(3))) void*)(unsigned int)(uintptr_t)l,
      16, 0, 0);
}

// ---------------------------------------------------------------------------
// Kernel 1: modulated+demodulated weights -> bf16, PRE-SWIZZLED TILE LAYOUT.
// Tile T = ((b*9+tap)*2 + cot)*4 + kb is a 16KB LDS image: 128 rows (co) x
// 128B, value for (co,ci) at byte (srow*128) + ((2*(ci&63)) ^ ((co&7)<<4)).
// grid = B*Co blocks of 256 threads (thread = ci)
// ---------------------------------------------------------------------------
__global__ __launch_bounds__(256) void prep_k(
    const float* __restrict__ weight,    // [N][Co][Ci][3][3]
    const float* __restrict__ styles,    // [B][Ci]
    const float* __restrict__ selector,  // [B][N]
    unsigned short* __restrict__ wmod)   // tiled-swizzled, 9.44 MB
{
  int bid = blockIdx.x;
  int b = bid >> 8, co = bid & 255;
  int ci = threadIdx.x;

  float sel[NKER];
#pragma unroll
  for (int n = 0; n < NKER; ++n) sel[n] = selector[b * NKER + n];

  float a[9];
#pragma unroll
  for (int j = 0; j < 9; ++j) a[j] = 0.f;
#pragma unroll
  for (int n = 0; n < NKER; ++n) {
    const float* wp = weight + (size_t)((n * NCO + co) * NCI + ci) * 9;
    float s = sel[n];
#pragma unroll
    for (int j = 0; j < 9; ++j) a[j] += s * wp[j];
  }
  float st = styles[b * NCI + ci];
  float ss = 0.f;
#pragma unroll
  for (int j = 0; j < 9; ++j) { a[j] *= st; ss += a[j] * a[j]; }

  for (int off = 32; off; off >>= 1) ss += __shfl_down(ss, off, 64);
  __shared__ float red[4];
  int wid = threadIdx.x >> 6, lane = threadIdx.x & 63;
  if (lane == 0) red[wid] = ss;
  __syncthreads();
  float tot = red[0] + red[1] + red[2] + red[3];
  float d = rsqrtf(tot + 1e-8f);

  int cot = co >> 7, kb = ci >> 6;
  int pb = ((ci & 63) << 1) ^ ((co & 7) << 4);    // swizzled byte in row
#pragma unroll
  for (int j = 0; j < 9; ++j) {
    size_t T = (size_t)(((b * 9 + j) * 2 + cot) * 4 + kb);
    wmod[(T << 13) + ((co & 127) << 6) + (pb >> 1)] = f2bf(a[j] * d);
  }
}

// ---------------------------------------------------------------------------
// Kernel 2: implicit-GEMM conv, pipelined.
// block = (b, cot, h); 256 thr = 4 waves (2x2 grid, 64co x 64px each).
// Phase = (dh, kb): stage Al[3 taps] via global_load_lds + XR (reg->LDS),
// then 96 MFMA. Next phase's x loads stay in flight across the barrier
// (s_waitcnt vmcnt(8), never 0).
// ---------------------------------------------------------------------------
__global__ __launch_bounds__(256, 2) void conv_k(
    const float* __restrict__ x,              // [B][Ci][H][W] f32
    const unsigned short* __restrict__ wg,    // tiled-swizzled wmod
    const float* __restrict__ noise,          // [B][Co][H][W]
    float* __restrict__ out)                  // [B][Co][H][W]
{
  __shared__ __align__(16) unsigned short Al[3 * 128 * 64];  // 48KB
  __shared__ __align__(16) unsigned short XR[128 * 64];      // 16KB

  // XCD-aware swizzle: 2048 blocks, 8 XCDs -> XCD x owns sample b=x
  int orig = blockIdx.x;
  int bid = (orig & 7) * 256 + (orig >> 3);
  int b = bid >> 8;
  int r = bid & 255;
  int cot = r >> 7;
  int h = r & 127;
  int co0 = cot << 7;

  int t = threadIdx.x;
  int lane = t & 63;
  int wid = t >> 6;
  int wr = wid >> 1, wc = wid & 1;
  int ll = lane & 15;

  // phase bookkeeping: seg -> dh (skip invalid border rows uniformly)
  int dh0 = (h == 0) ? 1 : 0;
  int nseg = 3 - (h == 0) - (h == 127);
  int P = nseg << 2;

  f32x4 acc[4][4];
#pragma unroll
  for (int m = 0; m < 4; ++m)
#pragma unroll
    for (int n = 0; n < 4; ++n) acc[m][n] = (f32x4){0.f, 0.f, 0.f, 0.f};

  // XR staging assignment: thread owns ci-pair (bc,bc+1) x 16 w
  int bc = (t & 31) * 2;
  int bwg = t >> 5;

  f32x4 xa[4], xb[4], xna[4], xnb[4];

  auto issueXR = [&](int p, f32x4* ra, f32x4* rb) {
    int seg = p >> 2, kb = p & 3;
    int dh = seg + dh0;
    int hy = h + dh - 1;
    int ci0 = kb << 6;
    const f32x4* x40 = (const f32x4*)(x +
        ((size_t)(b * NCI + ci0 + bc) * NHW + hy) * NHW) + bwg * 4;
    const f32x4* x41 = x40 + (NHW * NHW / 4);
#pragma unroll
    for (int jj = 0; jj < 4; ++jj) { ra[jj] = x40[jj]; rb[jj] = x41[jj]; }
  };

  issueXR(0, xa, xb);   // prologue: 8 loads in flight

#pragma unroll 1
  for (int p = 0; p < P; ++p) {
    int seg = p >> 2, kb = p & 3;
    int dh = seg + dh0;
    int tb = dh * 3;

    __builtin_amdgcn_s_barrier();           // prev compute done; LDS free

    // ---- A: 48KB via global_load_lds (12 x 1KB chunks per wave) ----
    {
      const char* wgc = (const char*)wg;
#pragma unroll
      for (int i = 0; i < 12; ++i) {
        int c = wid * 12 + i;               // chunk 0..47
        int tap = c >> 4, off = c & 15;
        size_t T = (size_t)(((b * 9 + tb + tap) * 2 + cot) * 4 + kb);
        gl_lds16(wgc + (T << 14) + off * 1024 + lane * 16,
                 (char*)Al + (c << 10) + lane * 16);
      }
    }
    __builtin_amdgcn_sched_barrier(0);      // Al issues precede XRnext issues

    // ---- prefetch next phase's x rows into regs ----
    issueXR(p + 1 < P ? p + 1 : p, xna, xnb);
    __builtin_amdgcn_sched_barrier(0);      // XRnext issued before the waitcnt

    // ---- pack current x regs -> XR (swizzled) ----
#pragma unroll
    for (int jj = 0; jj < 4; ++jj) {
#pragma unroll
      for (int e = 0; e < 4; ++e) {
        int w = bwg * 16 + jj * 4 + e;
        unsigned int pk = ((unsigned int)f2bf(xb[jj][e]) << 16) | f2bf(xa[jj][e]);
        *(unsigned int*)((char*)XR + w * 128 + ((bc * 2) ^ ((w & 7) << 4))) = pk;
      }
    }

    // wait: Al in LDS (12) + XR ds_writes done; XRnext (8) stays in flight
    asm volatile("s_waitcnt vmcnt(8) lgkmcnt(0)" ::: "memory");
    __builtin_amdgcn_sched_barrier(0);
    __builtin_amdgcn_s_barrier();           // stage visible to all waves

    // ---- compute: 3 taps x 2 K-steps x 16 MFMA ----
#pragma unroll
    for (int tap3 = 0; tap3 < 3; ++tap3) {
      int dw = tap3;
#pragma unroll
      for (int ks = 0; ks < 2; ++ks) {
        int cib = ks * 64 + ((lane >> 4) << 4);
        s16x8 af[4], bf[4];
#pragma unroll
        for (int m = 0; m < 4; ++m) {
          int row = wr * 64 + m * 16 + ll;
          af[m] = *(const s16x8*)((const char*)Al + tap3 * 16384 + row * 128 +
                                  (cib ^ ((row & 7) << 4)));
        }
#pragma unroll
        for (int n = 0; n < 4; ++n) {
          int wn = wc * 64 + n * 16 + ll + dw - 1;
          // only (dw=0,n=0) can underflow and (dw=2,n=3) overflow
          if ((dw == 0 && n == 0) || (dw == 2 && n == 3)) {
            int wx = wn < 0 ? 0 : (wn > 127 ? 127 : wn);
            s16x8 bv = *(const s16x8*)((const char*)XR + wx * 128 +
                                       (cib ^ ((wx & 7) << 4)));
            if (wn != wx) { s16x8 z = {0,0,0,0,0,0,0,0}; bv = z; }
            bf[n] = bv;
          } else {
            bf[n] = *(const s16x8*)((const char*)XR + wn * 128 +
                                    (cib ^ ((wn & 7) << 4)));
          }
        }
#pragma unroll
        for (int m = 0; m < 4; ++m)
#pragma unroll
          for (int n = 0; n < 4; ++n)
            acc[m][n] = __builtin_amdgcn_mfma_f32_16x16x32_bf16(
                af[m], bf[n], acc[m][n], 0, 0, 0);
      }
    }

    // rotate prefetch regs
#pragma unroll
    for (int jj = 0; jj < 4; ++jj) { xa[jj] = xna[jj]; xb[jj] = xnb[jj]; }
  }

  // epilogue: D[row=(lane>>4)*4+j][col=lane&15], fused noise add
  int pc = ll;
  int pr4 = (lane >> 4) * 4;
#pragma unroll
  for (int m = 0; m < 4; ++m) {
#pragma unroll
    for (int n = 0; n < 4; ++n) {
      int px = wc * 64 + n * 16 + pc;
#pragma unroll
      for (int j = 0; j < 4; ++j) {
        int co = co0 + wr * 64 + m * 16 + pr4 + j;
        size_t idx = ((size_t)(b * NCO + co) * NHW + h) * NHW + px;
        out[idx] = acc[m][n][j] + noise[idx];
      }
    }
  }
}

// ---------------------------------------------------------------------------
extern "C" void kernel_launch(void* const* d_in, const int* in_sizes, int n_in,
                              void* d_out, int out_size, void* d_ws, size_t ws_size,
                              hipStream_t stream) {
  const float* x        = (const float*)d_in[0];
  const float* weight   = (const float*)d_in[1];
  const float* styles   = (const float*)d_in[2];
  const float* selector = (const float*)d_in[3];
  const float* noise    = (const float*)d_in[4];
  float* out = (float*)d_out;

  // workspace: ONLY wmod (tiled-swizzled) = 9,437,184 bytes
  unsigned short* wmod = (unsigned short*)d_ws;

  hipLaunchKernelGGL(prep_k, dim3(NB * NCO), dim3(256), 0, stream,
                     weight, styles, selector, wmod);
  hipLaunchKernelGGL(conv_k, dim3(NB * 2 * NHW), dim3(256), 0, stream,
                     x, wmod, noise, out);
}